// Round 5
// baseline (311.837 us; speedup 1.0000x reference)
//
#include <hip/hip_runtime.h>
#include <hip/hip_bf16.h>

// SparseLinear as dense bf16 MFMA GEMM: out[b,o] = sum_i x[b,i]*W[o,i]
// C = A * B^T, M=8192, N=4096, K=4096. bias is dead in the reference.
// R5: co-residency design — 256-thread blocks (4 waves), 256x128 tile,
// BK=32, TRIPLE-buffered LDS (72 KiB) => 2 independent blocks/CU whose
// phases interleave (cross-block MFMA/LDS overlap, m114). 32x32x16 MFMA
// (higher ceiling than 16x16x32). One barrier + one counted vmcnt per
// K-tile, prefetch depth 2. T1 XCD swizzle + T2 LDS XOR swizzle + T5.

typedef short bf16x8 __attribute__((ext_vector_type(8)));
typedef float f32x4 __attribute__((ext_vector_type(4)));
typedef float f32x16 __attribute__((ext_vector_type(16)));
typedef unsigned short u16x8 __attribute__((ext_vector_type(8)));

static constexpr int M_DIM = 8192;
static constexpr int N_DIM = 4096;
static constexpr int K_DIM = 4096;
static constexpr int BM = 256, BN = 128, BK = 32;
static constexpr int KT = K_DIM / BK;  // 128 K-tiles
static constexpr int BUF_SH = 12288;   // shorts per buffer: A 16KB + B 8KB

__device__ __forceinline__ unsigned short f2bf(float f) {
  unsigned int u = __builtin_bit_cast(unsigned int, f);
  u += 0x7fffu + ((u >> 16) & 1u);
  return (unsigned short)(u >> 16);
}

__global__ void cvt_f32_bf16(const float* __restrict__ in,
                             unsigned short* __restrict__ out, long n8) {
  long i = (long)blockIdx.x * blockDim.x + threadIdx.x;
  const long stride = (long)gridDim.x * blockDim.x;
  for (; i < n8; i += stride) {
    f32x4 a = ((const f32x4*)in)[2 * i];
    f32x4 b = ((const f32x4*)in)[2 * i + 1];
    u16x8 v;
    v[0] = f2bf(a[0]); v[1] = f2bf(a[1]); v[2] = f2bf(a[2]); v[3] = f2bf(a[3]);
    v[4] = f2bf(b[0]); v[5] = f2bf(b[1]); v[6] = f2bf(b[2]); v[7] = f2bf(b[3]);
    ((u16x8*)out)[i] = v;
  }
}

// Buffer layout (bytes, per buffer): A-part [256 rows][32 k] at 0 (16 KB),
// B-part [128 rows][32 k] at 16384 (8 KB). Row stride 64 B.
// T2 swizzle (involution): byte ^= ((byte>>7)&3)<<4 (part-relative).
// Staging writes linearly (gload_lds), sources inverse-swizzled per-lane.

#define LGKM(N) asm volatile("s_waitcnt lgkmcnt(" #N ")" ::: "memory")
#define VMC(N) asm volatile("s_waitcnt vmcnt(" #N ")" ::: "memory")
#define BAR()                        \
  do {                               \
    asm volatile("" ::: "memory");   \
    __builtin_amdgcn_s_barrier();    \
    asm volatile("" ::: "memory");   \
  } while (0)

__device__ __forceinline__ void gload16(const unsigned short* src,
                                        unsigned short* dst) {
  __builtin_amdgcn_global_load_lds(
      (const __attribute__((address_space(1))) void*)src,
      (__attribute__((address_space(3))) void*)dst, 16, 0, 0);
}

__global__ __launch_bounds__(256, 2) void gemm32(
    const unsigned short* __restrict__ Ab, const unsigned short* __restrict__ Bb,
    float* __restrict__ C) {
  __shared__ unsigned short lds[3][BUF_SH];  // 72 KiB -> 2 blocks/CU

  const int tid = threadIdx.x;
  const int lane = tid & 63;
  const int wid = tid >> 6;   // 4 waves, 2x2 grid; wave-tile 128x64
  const int wr = wid >> 1;    // M half (128 rows)
  const int wc = wid & 1;     // N half (64 cols)
  const int l31 = lane & 31;
  const int lh = lane >> 5;

  // T1: XCD-aware bijective swizzle (grid 1024, %8==0)
  const int b0i = blockIdx.x;
  const int swz = (b0i & 7) * ((int)gridDim.x >> 3) + (b0i >> 3);
  const int row0 = (swz / (N_DIM / BN)) * BM;
  const int col0 = (swz % (N_DIM / BN)) * BN;

  // LDS read bases (part-relative logical -> swizzled). ks1 base = ks0 ^ 32
  // (logical bit5 is 0 pre-add, XOR bits 4-5 commute via ^).
  int ao = (wr * 128 + l31) * 64 + lh * 16;
  ao ^= ((ao >> 7) & 3) << 4;
  int bo = (wc * 64 + l31) * 64 + lh * 16;
  bo ^= ((bo >> 7) & 3) << 4;
  bo += 16384;  // B-part byte base (swizzle-invariant bit)
  const int ao1 = ao ^ 32, bo1 = bo ^ 32;

  // staging source pointers (inverse-swizzled, fixed; +k per tile)
  const unsigned short* pA[4];
  const unsigned short* pB[2];
#pragma unroll
  for (int r = 0; r < 4; ++r) {
    int q = r * 4096 + tid * 16;
    int lo = q ^ (((q >> 7) & 3) << 4);
    pA[r] = Ab + (size_t)(row0 + (lo >> 6)) * K_DIM + ((lo & 63) >> 1);
  }
#pragma unroll
  for (int r = 0; r < 2; ++r) {
    int q = r * 4096 + tid * 16;
    int lo = q ^ (((q >> 7) & 3) << 4);
    pB[r] = Bb + (size_t)(col0 + (lo >> 6)) * K_DIM + ((lo & 63) >> 1);
  }

  f32x16 acc[4][2] = {};

  // prologue: stage tiles 0,1 (6 loads each)
#pragma unroll
  for (int r = 0; r < 4; ++r) gload16(pA[r], &lds[0][0] + r * 2048 + wid * 512);
#pragma unroll
  for (int r = 0; r < 2; ++r) gload16(pB[r], &lds[0][0] + 8192 + r * 2048 + wid * 512);
#pragma unroll
  for (int r = 0; r < 4; ++r) gload16(pA[r] + 32, &lds[1][0] + r * 2048 + wid * 512);
#pragma unroll
  for (int r = 0; r < 2; ++r) gload16(pB[r] + 32, &lds[1][0] + 8192 + r * 2048 + wid * 512);

  int cur = 0;
#pragma unroll 1
  for (int t = 0; t < KT; ++t) {
    const char* bc = (const char*)&lds[cur][0];
    // gate: tile t's 6 loads landed (t+1's 6 may stay in flight)
    if (t < KT - 1) { VMC(6); } else { VMC(0); }
    BAR();  // stage(t-1 -> this buf's successor) reads all done before this

    bf16x8 a0[4], a1[4], b0[2], b1[2];
#pragma unroll
    for (int mf = 0; mf < 4; ++mf) a0[mf] = *(const bf16x8*)(bc + ao + mf * 2048);
#pragma unroll
    for (int nf = 0; nf < 2; ++nf) b0[nf] = *(const bf16x8*)(bc + bo + nf * 2048);
    if (t + 2 < KT) {  // stage tile t+2 -> buf (cur+2)%3 (read at t-1, safe)
      int stg = cur ? cur - 1 : 2;
      unsigned short* Lb = &lds[stg][0];
      const int k = (t + 2) * 32;
#pragma unroll
      for (int r = 0; r < 4; ++r) gload16(pA[r] + k, Lb + r * 2048 + wid * 512);
#pragma unroll
      for (int r = 0; r < 2; ++r) gload16(pB[r] + k, Lb + 8192 + r * 2048 + wid * 512);
    }
#pragma unroll
    for (int mf = 0; mf < 4; ++mf) a1[mf] = *(const bf16x8*)(bc + ao1 + mf * 2048);
#pragma unroll
    for (int nf = 0; nf < 2; ++nf) b1[nf] = *(const bf16x8*)(bc + bo1 + nf * 2048);

    LGKM(6);  // ks0's 6 reads done; ks1's 6 may be in flight
    __builtin_amdgcn_sched_barrier(0);
    __builtin_amdgcn_s_setprio(1);
#pragma unroll
    for (int mf = 0; mf < 4; ++mf)
#pragma unroll
      for (int nf = 0; nf < 2; ++nf)
        acc[mf][nf] = __builtin_amdgcn_mfma_f32_32x32x16_bf16(a0[mf], b0[nf], acc[mf][nf], 0, 0, 0);
    __builtin_amdgcn_s_setprio(0);
    LGKM(0);
    __builtin_amdgcn_sched_barrier(0);
    __builtin_amdgcn_s_setprio(1);
#pragma unroll
    for (int mf = 0; mf < 4; ++mf)
#pragma unroll
      for (int nf = 0; nf < 2; ++nf)
        acc[mf][nf] = __builtin_amdgcn_mfma_f32_32x32x16_bf16(a1[mf], b1[nf], acc[mf][nf], 0, 0, 0);
    __builtin_amdgcn_s_setprio(0);

    cur = (cur == 2) ? 0 : cur + 1;
  }

  // epilogue: 32x32 C/D layout (m74/m101): col=lane&31,
  // row = (reg&3) + 8*(reg>>2) + 4*(lane>>5)
#pragma unroll
  for (int mf = 0; mf < 4; ++mf) {
#pragma unroll
    for (int nf = 0; nf < 2; ++nf) {
      const int gr = row0 + wr * 128 + mf * 32 + 4 * lh;
      const int gc = col0 + wc * 64 + nf * 32 + l31;
      float* cp = C + (size_t)gr * N_DIM + gc;
#pragma unroll
      for (int g = 0; g < 4; ++g)
#pragma unroll
        for (int j = 0; j < 4; ++j)
          cp[(size_t)(8 * g + j) * N_DIM] = acc[mf][nf][g * 4 + j];
    }
  }
}

// ---- fallback (ws too small): reg-staged f32->bf16 kernel ------------------
__global__ __launch_bounds__(256) void gemm_fb(const float* __restrict__ Af,
                                               const float* __restrict__ Bf,
                                               float* __restrict__ C) {
  __shared__ unsigned short sA[128 * 64];
  __shared__ unsigned short sB[128 * 64];
  const int tid = threadIdx.x;
  const int lane = tid & 63;
  const int wid = tid >> 6;
  const int wr = wid >> 1, wc = wid & 1;
  const int cpx = (int)gridDim.x >> 3;
  const int swzb = ((int)blockIdx.x & 7) * cpx + ((int)blockIdx.x >> 3);
  const int row0 = (swzb / (N_DIM / 128)) * 128;
  const int col0 = (swzb % (N_DIM / 128)) * 128;
  f32x4 acc[4][4] = {};
  const int fbase = tid * 8;
  for (int kt = 0; kt < K_DIM; kt += 64) {
#pragma unroll
    for (int p = 0; p < 4; ++p) {
      const int f = fbase + p * 2048;
      const int r = f >> 6, kc = f & 63;
      const float* gA = Af + (size_t)(row0 + r) * K_DIM + kt + kc;
      const float* gB = Bf + (size_t)(col0 + r) * K_DIM + kt + kc;
      f32x4 a0 = ((const f32x4*)gA)[0], a1 = ((const f32x4*)gA)[1];
      f32x4 c0 = ((const f32x4*)gB)[0], c1 = ((const f32x4*)gB)[1];
      u16x8 va, vb;
      va[0] = f2bf(a0[0]); va[1] = f2bf(a0[1]); va[2] = f2bf(a0[2]); va[3] = f2bf(a0[3]);
      va[4] = f2bf(a1[0]); va[5] = f2bf(a1[1]); va[6] = f2bf(a1[2]); va[7] = f2bf(a1[3]);
      vb[0] = f2bf(c0[0]); vb[1] = f2bf(c0[1]); vb[2] = f2bf(c0[2]); vb[3] = f2bf(c0[3]);
      vb[4] = f2bf(c1[0]); vb[5] = f2bf(c1[1]); vb[6] = f2bf(c1[2]); vb[7] = f2bf(c1[3]);
      *(u16x8*)&sA[f] = va;
      *(u16x8*)&sB[f] = vb;
    }
    __syncthreads();
#pragma unroll
    for (int kk = 0; kk < 2; ++kk) {
      bf16x8 a[4], b[4];
#pragma unroll
      for (int m = 0; m < 4; ++m)
        a[m] = *(const bf16x8*)&sA[(wr * 64 + m * 16 + (lane & 15)) * 64 + kk * 32 + (lane >> 4) * 8];
#pragma unroll
      for (int n = 0; n < 4; ++n)
        b[n] = *(const bf16x8*)&sB[(wc * 64 + n * 16 + (lane & 15)) * 64 + kk * 32 + (lane >> 4) * 8];
#pragma unroll
      for (int m = 0; m < 4; ++m)
#pragma unroll
        for (int n = 0; n < 4; ++n)
          acc[m][n] = __builtin_amdgcn_mfma_f32_16x16x32_bf16(a[m], b[n], acc[m][n], 0, 0, 0);
    }
    __syncthreads();
  }
#pragma unroll
  for (int m = 0; m < 4; ++m)
#pragma unroll
    for (int n = 0; n < 4; ++n) {
      const int gr = row0 + wr * 64 + m * 16 + (lane >> 4) * 4;
      const int gc = col0 + wc * 64 + n * 16 + (lane & 15);
      float* cp = C + (size_t)gr * N_DIM + gc;
#pragma unroll
      for (int j = 0; j < 4; ++j) cp[(size_t)j * N_DIM] = acc[m][n][j];
    }
}

extern "C" void kernel_launch(void* const* d_in, const int* in_sizes, int n_in,
                              void* d_out, int out_size, void* d_ws, size_t ws_size,
                              hipStream_t stream) {
  const float* x = (const float*)d_in[0];  // [8192, 4096]
  const float* W = (const float*)d_in[1];  // [4096, 4096]
  float* out = (float*)d_out;              // [8192, 4096] f32

  const size_t xb_bytes = (size_t)M_DIM * K_DIM * 2;  // 64 MiB
  const size_t wb_bytes = (size_t)N_DIM * K_DIM * 2;  // 32 MiB

  if (ws_size >= xb_bytes + wb_bytes) {
    unsigned short* Xb = (unsigned short*)d_ws;
    unsigned short* Wb = (unsigned short*)((char*)d_ws + xb_bytes);
    cvt_f32_bf16<<<2048, 256, 0, stream>>>(x, Xb, (long)M_DIM * K_DIM / 8);
    cvt_f32_bf16<<<2048, 256, 0, stream>>>(W, Wb, (long)N_DIM * K_DIM / 8);
    const dim3 grid((M_DIM / BM) * (N_DIM / BN));  // 32*32 = 1024 blocks
    gemm32<<<grid, dim3(256), 0, stream>>>(Xb, Wb, out);
  } else {
    gemm_fb<<<dim3(2048), dim3(256), 0, stream>>>(x, W, out);
  }
}

// Round 7
// 282.381 us; speedup vs baseline: 1.1043x; 1.1043x over previous
//
#include <hip/hip_runtime.h>
#include <hip/hip_bf16.h>

// SparseLinear as dense bf16 MFMA GEMM: out[b,o] = sum_i x[b,i]*W[o,i]
// C = A * B^T, M=8192, N=4096, K=4096. bias is dead in the reference.
// R7 = R6 structure with the kk-offset ADD->XOR fix (swizzle bits 5-6
// collide with kk-offset bits; XOR is the involution-correct compose,
// ADD carried into row bits and past region ends -> NaN).
// 256x256 tile, BK=64, 8 waves, whole-tile double buffer (128 KiB),
// ONE barrier + ONE vmcnt(0) per K-tile, no intra-tile barriers (waves
// free-run/de-phase: LDS service of one wave overlaps MFMA of another).
// 32x32x16 MFMA. T1 XCD swizzle; T2 3-bit XOR swizzle ((row&7)<<4).

typedef short bf16x8 __attribute__((ext_vector_type(8)));
typedef float f32x4 __attribute__((ext_vector_type(4)));
typedef float f32x16 __attribute__((ext_vector_type(16)));
typedef unsigned short u16x8 __attribute__((ext_vector_type(8)));

static constexpr int M_DIM = 8192;
static constexpr int N_DIM = 4096;
static constexpr int K_DIM = 4096;
static constexpr int BM = 256, BN = 256, BK = 64;
static constexpr int KT = K_DIM / BK;  // 64 K-tiles

__device__ __forceinline__ unsigned short f2bf(float f) {
  unsigned int u = __builtin_bit_cast(unsigned int, f);
  u += 0x7fffu + ((u >> 16) & 1u);
  return (unsigned short)(u >> 16);
}

__global__ void cvt_f32_bf16(const float* __restrict__ in,
                             unsigned short* __restrict__ out, long n8) {
  long i = (long)blockIdx.x * blockDim.x + threadIdx.x;
  const long stride = (long)gridDim.x * blockDim.x;
  for (; i < n8; i += stride) {
    f32x4 a = ((const f32x4*)in)[2 * i];
    f32x4 b = ((const f32x4*)in)[2 * i + 1];
    u16x8 v;
    v[0] = f2bf(a[0]); v[1] = f2bf(a[1]); v[2] = f2bf(a[2]); v[3] = f2bf(a[3]);
    v[4] = f2bf(b[0]); v[5] = f2bf(b[1]); v[6] = f2bf(b[2]); v[7] = f2bf(b[3]);
    ((u16x8*)out)[i] = v;
  }
}

// LDS buffer layout (bytes, per buffer): A [256 rows][64 k] at 0 (32 KB),
// B [256 rows][64 k] at 32768 (32 KB). Row stride 128 B.
// Swizzle (involution): byte ^= ((byte>>7)&7)<<4 — bank bits 4-6 XOR row
// bits 0-2. Read pattern (row=l31, lh in bit4): 8 uniform groups x 4 banks
// = conflict-free. Offsets: m/n*4096 (bits>=12) ADD is safe; kk offsets
// 32/64/96 (bits 5-6) must XOR onto the swizzled base.

#define VMC0() asm volatile("s_waitcnt vmcnt(0)" ::: "memory")
#define BAR()                        \
  do {                               \
    asm volatile("" ::: "memory");   \
    __builtin_amdgcn_s_barrier();    \
    asm volatile("" ::: "memory");   \
  } while (0)

__device__ __forceinline__ void gload16(const unsigned short* src,
                                        unsigned short* dst) {
  __builtin_amdgcn_global_load_lds(
      (const __attribute__((address_space(1))) void*)src,
      (__attribute__((address_space(3))) void*)dst, 16, 0, 0);
}

__global__ __launch_bounds__(512, 2) void gemmR7(
    const unsigned short* __restrict__ Ab, const unsigned short* __restrict__ Bb,
    float* __restrict__ C) {
  __shared__ unsigned short lds[2][32768];  // 128 KiB

  const int tid = threadIdx.x;
  const int lane = tid & 63;
  const int wid = tid >> 6;   // 8 waves, 2M x 4N; wave-tile 128x64
  const int wr = wid >> 2;    // 0..1
  const int wc = wid & 3;     // 0..3
  const int l31 = lane & 31;
  const int lh = lane >> 5;

  // T1: XCD-aware bijective swizzle (512 blocks, %8==0)
  const int b0i = blockIdx.x;
  const int swz = (b0i & 7) * ((int)gridDim.x >> 3) + (b0i >> 3);
  const int row0 = (swz / (N_DIM / BN)) * BM;
  const int col0 = (swz % (N_DIM / BN)) * BN;

  // swizzled read bases (bytes, buffer-relative)
  const int xorc = (l31 & 7) << 4;
  const int abase = (((wr * 128 + l31) * 128) + lh * 16) ^ xorc;
  const int bbase = ((((wc * 64 + l31) * 128) + lh * 16) ^ xorc) + 32768;

  // staging: per-thread inverse-swizzled global sources (fixed; +k per tile)
  const unsigned short* pA[4];
  const unsigned short* pB[4];
#pragma unroll
  for (int r = 0; r < 4; ++r) {
    int q = r * 8192 + tid * 16;             // linear byte pos in region
    int lo = q ^ (((q >> 7) & 7) << 4);      // logical (row,k)
    pA[r] = Ab + (size_t)(row0 + (lo >> 7)) * K_DIM + ((lo & 127) >> 1);
    pB[r] = Bb + (size_t)(col0 + (lo >> 7)) * K_DIM + ((lo & 127) >> 1);
  }

  f32x16 acc[4][2] = {};

  // prologue: stage tile 0 -> buf 0 (8 gloads)
#pragma unroll
  for (int r = 0; r < 4; ++r) {
    gload16(pA[r], &lds[0][0] + r * 4096 + wid * 512);
    gload16(pB[r], &lds[0][0] + 16384 + r * 4096 + wid * 512);
  }

  bf16x8 aE[4], bE[2], aO[4], bO[2];  // even/odd kk operand sets

#pragma unroll 1
  for (int t = 0; t < KT; ++t) {
    const char* bc = (const char*)&lds[t & 1][0];
    unsigned short* dn = &lds[(t & 1) ^ 1][0] + wid * 512;

    VMC0();  // tile t's 8 loads landed (issued >=1 tile of MFMA ago)
    BAR();   // all waves' reads of the other buffer retired (each read is
             // consumed by an MFMA before this wave reaches the barrier)

    // kk0 + kk1 reads (XOR-composed kk offsets; compiler inserts lgkmcnt)
#pragma unroll
    for (int m = 0; m < 4; ++m)
      aE[m] = *(const bf16x8*)(bc + ((abase + m * 4096) ^ 0));
#pragma unroll
    for (int n = 0; n < 2; ++n)
      bE[n] = *(const bf16x8*)(bc + ((bbase + n * 4096) ^ 0));
#pragma unroll
    for (int m = 0; m < 4; ++m)
      aO[m] = *(const bf16x8*)(bc + ((abase + m * 4096) ^ 32));
#pragma unroll
    for (int n = 0; n < 2; ++n)
      bO[n] = *(const bf16x8*)(bc + ((bbase + n * 4096) ^ 32));

    // MFMA kk0
#pragma unroll
    for (int m = 0; m < 4; ++m)
#pragma unroll
      for (int n = 0; n < 2; ++n)
        acc[m][n] = __builtin_amdgcn_mfma_f32_32x32x16_bf16(aE[m], bE[n], acc[m][n], 0, 0, 0);

    // kk2 reads (into even set)
#pragma unroll
    for (int m = 0; m < 4; ++m)
      aE[m] = *(const bf16x8*)(bc + ((abase + m * 4096) ^ 64));
#pragma unroll
    for (int n = 0; n < 2; ++n)
      bE[n] = *(const bf16x8*)(bc + ((bbase + n * 4096) ^ 64));

    // MFMA kk1
#pragma unroll
    for (int m = 0; m < 4; ++m)
#pragma unroll
      for (int n = 0; n < 2; ++n)
        acc[m][n] = __builtin_amdgcn_mfma_f32_32x32x16_bf16(aO[m], bO[n], acc[m][n], 0, 0, 0);

    // kk3 reads (into odd set)
#pragma unroll
    for (int m = 0; m < 4; ++m)
      aO[m] = *(const bf16x8*)(bc + ((abase + m * 4096) ^ 96));
#pragma unroll
    for (int n = 0; n < 2; ++n)
      bO[n] = *(const bf16x8*)(bc + ((bbase + n * 4096) ^ 96));

    // stage tile t+1 -> other buffer (after all reads of this tile issued;
    // ~2 MFMA clusters cover HBM latency before the next-tile vmcnt gate)
    if (t + 1 < KT) {
      const int k = (t + 1) * 64;
#pragma unroll
      for (int r = 0; r < 4; ++r) {
        gload16(pA[r] + k, dn + r * 4096);
        gload16(pB[r] + k, dn + 16384 + r * 4096);
      }
    }

    // MFMA kk2
#pragma unroll
    for (int m = 0; m < 4; ++m)
#pragma unroll
      for (int n = 0; n < 2; ++n)
        acc[m][n] = __builtin_amdgcn_mfma_f32_32x32x16_bf16(aE[m], bE[n], acc[m][n], 0, 0, 0);

    // MFMA kk3
#pragma unroll
    for (int m = 0; m < 4; ++m)
#pragma unroll
      for (int n = 0; n < 2; ++n)
        acc[m][n] = __builtin_amdgcn_mfma_f32_32x32x16_bf16(aO[m], bO[n], acc[m][n], 0, 0, 0);
  }

  // epilogue: 32x32 C/D layout (m74/m101, R5-validated):
  // col = lane&31, row = (reg&3) + 8*(reg>>2) + 4*(lane>>5)
#pragma unroll
  for (int mf = 0; mf < 4; ++mf) {
#pragma unroll
    for (int nf = 0; nf < 2; ++nf) {
      const int gr = row0 + wr * 128 + mf * 32 + 4 * lh;
      const int gc = col0 + wc * 64 + nf * 32 + l31;
      float* cp = C + (size_t)gr * N_DIM + gc;
#pragma unroll
      for (int g = 0; g < 4; ++g)
#pragma unroll
        for (int j = 0; j < 4; ++j)
          cp[(size_t)(8 * g + j) * N_DIM] = acc[mf][nf][g * 4 + j];
    }
  }
}

// ---- fallback (ws too small): reg-staged f32->bf16 kernel ------------------
__global__ __launch_bounds__(256) void gemm_fb(const float* __restrict__ Af,
                                               const float* __restrict__ Bf,
                                               float* __restrict__ C) {
  __shared__ unsigned short sA[128 * 64];
  __shared__ unsigned short sB[128 * 64];
  const int tid = threadIdx.x;
  const int lane = tid & 63;
  const int wid = tid >> 6;
  const int wr = wid >> 1, wc = wid & 1;
  const int cpx = (int)gridDim.x >> 3;
  const int swzb = ((int)blockIdx.x & 7) * cpx + ((int)blockIdx.x >> 3);
  const int row0 = (swzb / (N_DIM / 128)) * 128;
  const int col0 = (swzb % (N_DIM / 128)) * 128;
  f32x4 acc[4][4] = {};
  const int fbase = tid * 8;
  for (int kt = 0; kt < K_DIM; kt += 64) {
#pragma unroll
    for (int p = 0; p < 4; ++p) {
      const int f = fbase + p * 2048;
      const int r = f >> 6, kc = f & 63;
      const float* gA = Af + (size_t)(row0 + r) * K_DIM + kt + kc;
      const float* gB = Bf + (size_t)(col0 + r) * K_DIM + kt + kc;
      f32x4 a0 = ((const f32x4*)gA)[0], a1 = ((const f32x4*)gA)[1];
      f32x4 c0 = ((const f32x4*)gB)[0], c1 = ((const f32x4*)gB)[1];
      u16x8 va, vb;
      va[0] = f2bf(a0[0]); va[1] = f2bf(a0[1]); va[2] = f2bf(a0[2]); va[3] = f2bf(a0[3]);
      va[4] = f2bf(a1[0]); va[5] = f2bf(a1[1]); va[6] = f2bf(a1[2]); va[7] = f2bf(a1[3]);
      vb[0] = f2bf(c0[0]); vb[1] = f2bf(c0[1]); vb[2] = f2bf(c0[2]); vb[3] = f2bf(c0[3]);
      vb[4] = f2bf(c1[0]); vb[5] = f2bf(c1[1]); vb[6] = f2bf(c1[2]); vb[7] = f2bf(c1[3]);
      *(u16x8*)&sA[f] = va;
      *(u16x8*)&sB[f] = vb;
    }
    __syncthreads();
#pragma unroll
    for (int kk = 0; kk < 2; ++kk) {
      bf16x8 a[4], b[4];
#pragma unroll
      for (int m = 0; m < 4; ++m)
        a[m] = *(const bf16x8*)&sA[(wr * 64 + m * 16 + (lane & 15)) * 64 + kk * 32 + (lane >> 4) * 8];
#pragma unroll
      for (int n = 0; n < 4; ++n)
        b[n] = *(const bf16x8*)&sB[(wc * 64 + n * 16 + (lane & 15)) * 64 + kk * 32 + (lane >> 4) * 8];
#pragma unroll
      for (int m = 0; m < 4; ++m)
#pragma unroll
        for (int n = 0; n < 4; ++n)
          acc[m][n] = __builtin_amdgcn_mfma_f32_16x16x32_bf16(a[m], b[n], acc[m][n], 0, 0, 0);
    }
    __syncthreads();
  }
#pragma unroll
  for (int m = 0; m < 4; ++m)
#pragma unroll
    for (int n = 0; n < 4; ++n) {
      const int gr = row0 + wr * 64 + m * 16 + (lane >> 4) * 4;
      const int gc = col0 + wc * 64 + n * 16 + (lane & 15);
      float* cp = C + (size_t)gr * N_DIM + gc;
#pragma unroll
      for (int j = 0; j < 4; ++j) cp[(size_t)j * N_DIM] = acc[m][n][j];
    }
}

extern "C" void kernel_launch(void* const* d_in, const int* in_sizes, int n_in,
                              void* d_out, int out_size, void* d_ws, size_t ws_size,
                              hipStream_t stream) {
  const float* x = (const float*)d_in[0];  // [8192, 4096]
  const float* W = (const float*)d_in[1];  // [4096, 4096]
  float* out = (float*)d_out;              // [8192, 4096] f32

  const size_t xb_bytes = (size_t)M_DIM * K_DIM * 2;  // 64 MiB
  const size_t wb_bytes = (size_t)N_DIM * K_DIM * 2;  // 32 MiB

  if (ws_size >= xb_bytes + wb_bytes) {
    unsigned short* Xb = (unsigned short*)d_ws;
    unsigned short* Wb = (unsigned short*)((char*)d_ws + xb_bytes);
    cvt_f32_bf16<<<2048, 256, 0, stream>>>(x, Xb, (long)M_DIM * K_DIM / 8);
    cvt_f32_bf16<<<2048, 256, 0, stream>>>(W, Wb, (long)N_DIM * K_DIM / 8);
    const dim3 grid((M_DIM / BM) * (N_DIM / BN));  // 32*16 = 512 blocks
    gemmR7<<<grid, dim3(512), 0, stream>>>(Xb, Wb, out);
  } else {
    gemm_fb<<<dim3(2048), dim3(256), 0, stream>>>(x, W, out);
  }
}